// Round 2
// baseline (136.057 us; speedup 1.0000x reference)
//
#include <hip/hip_runtime.h>
#include <math.h>

#define NF   640
#define IMGN 256
#define NPIX (IMGN * IMGN)
#define TEXN 6

// One block = 256 consecutive pixels (one image row). Each block first
// cooperatively computes per-face raster data into LDS, then each thread
// rasterizes its pixel against all 640 faces.
//
// CORRECTNESS CONTRACT: the inside/depth/argmin decisions must be bit-exact
// vs the numpy float32 reference. Therefore:
//  - fp contract OFF (numpy never fuses mul+add; hipcc default would)
//  - true IEEE '/' by det_s (NOT reciprocal-multiply)
//  - identical op order everywhere on the decision path
//  - wfov = tan(deg2rad(45f)) = 1.0f exactly (correctly-rounded f32)
__global__ __launch_bounds__(256) void render_kernel(
    const float* __restrict__ verts,   // 400*3 f32
    const int*   __restrict__ faces,   // 640*3 i32
    const float* __restrict__ tex,     // 640*6*6*6*3 f32
    float* __restrict__ out)           // 3*65536 f32 (planar CHW)
{
#pragma clang fp contract(off)
    __shared__ float sV0X[NF], sV0Y[NF], sDX[NF], sDY[NF], sEX[NF], sEY[NF];
    __shared__ float sDET[NF], sZ0[NF], sZ1[NF], sZ2[NF], sL[NF];
    __shared__ unsigned char sOK[NF];

    const float EPSf = 1e-8f;
    const float wfov = 1.0f; // tan(f32(deg2rad(45))) correctly rounded

    // ---- per-face prep (camera rotation is exactly identity in f32) ----
    for (int f = (int)threadIdx.x; f < NF; f += (int)blockDim.x) {
        int ia = faces[3 * f + 0];
        int ib = faces[3 * f + 1];
        int ic = faces[3 * f + 2];
        float ax = verts[3 * ia], ay = verts[3 * ia + 1], az = verts[3 * ia + 2];
        float bx = verts[3 * ib], by = verts[3 * ib + 1], bz = verts[3 * ib + 2];
        float cx = verts[3 * ic], cy = verts[3 * ic + 1], cz = verts[3 * ic + 2];

        // lighting: light = 0.5 + 0.5*relu(nz / (|n|+eps))  (value-only path)
        float e1x = bx - ax, e1y = by - ay, e1z = bz - az;
        float e2x = cx - ax, e2y = cy - ay, e2z = cz - az;
        float nx = e1y * e2z - e1z * e2y;
        float ny = e1z * e2x - e1x * e2z;
        float nz = e1x * e2y - e1y * e2x;
        float nn = sqrtf((nx * nx + ny * ny) + nz * nz) + EPSf;
        float diff = nz / nn;
        diff = diff > 0.0f ? diff : 0.0f;
        float light = 0.5f + 0.5f * diff;

        // camera space: vc = v - eye = [x, y, z+2]; project (decision path)
        float z0 = az + 2.0f, z1 = bz + 2.0f, z2 = cz + 2.0f;
        float den0 = z0 * wfov + EPSf;
        float den1 = z1 * wfov + EPSf;
        float den2 = z2 * wfov + EPSf;
        float px0 = ax / den0, py0v = ay / den0;
        float px1 = bx / den1, py1v = by / den1;
        float px2 = cx / den2, py2v = cy / den2;

        float dx = px1 - px0, dy = py1v - py0v;
        float ex = px2 - px0, ey = py2v - py0v;
        float det = dx * ey - dy * ex;
        int ok = fabsf(det) > 1e-8f;
        float dets = ok ? det : 1.0f;

        sV0X[f] = px0; sV0Y[f] = py0v;
        sDX[f] = dx;   sDY[f] = dy;
        sEX[f] = ex;   sEY[f] = ey;
        sDET[f] = dets;
        sZ0[f] = z0;   sZ1[f] = z1;  sZ2[f] = z2;
        sL[f] = light;
        sOK[f] = (unsigned char)ok;
    }
    __syncthreads();

    // ---- per-pixel raster ----
    int p  = (int)(blockIdx.x * blockDim.x + threadIdx.x);
    int pi = p >> 8;         // row i
    int pj = p & (IMGN - 1); // col j
    // ps ops are all power-of-2 exact; matches numpy bitwise
    float ppx = ((pj + 0.5f) / (float)IMGN) * 2.0f - 1.0f;
    float ppy = -(((pi + 0.5f) / (float)IMGN) * 2.0f - 1.0f);

    float best = 1e30f;
    int   bi = -1;
    float bw0 = 0.0f, bw1 = 0.0f, bw2 = 0.0f;

    for (int f = 0; f < NF; ++f) {
        float qx = ppx - sV0X[f];
        float qy = ppy - sV0Y[f];
        float dets = sDET[f];
        // IEEE division, same op order as reference, no FMA contraction
        float w1 = (qx * sEY[f] - qy * sEX[f]) / dets;
        float w2 = (sDX[f] * qy - sDY[f] * qx) / dets;
        float w0 = (1.0f - w1) - w2;
        float depth = ((w0 * sZ0[f]) + (w1 * sZ1[f])) + (w2 * sZ2[f]);
        // strict '<' => first-occurrence argmin, matching jnp.argmin
        if (w0 >= 0.0f && w1 >= 0.0f && w2 >= 0.0f && sOK[f] &&
            depth > 0.0f && depth < best) {
            best = depth; bi = f; bw0 = w0; bw1 = w1; bw2 = w2;
        }
    }

    float r = 0.0f, g = 0.0f, b = 0.0f;
    if (bi >= 0) {
        int i0 = (int)(bw0 * (float)TEXN);
        int i1 = (int)(bw1 * (float)TEXN);
        int i2 = (int)(bw2 * (float)TEXN);
        i0 = i0 < 0 ? 0 : (i0 > TEXN - 1 ? TEXN - 1 : i0);
        i1 = i1 < 0 ? 0 : (i1 > TEXN - 1 ? TEXN - 1 : i1);
        i2 = i2 < 0 ? 0 : (i2 > TEXN - 1 ? TEXN - 1 : i2);
        const float* tp = tex + (size_t)((((bi * TEXN + i0) * TEXN + i1) * TEXN + i2) * 3);
        float light = sL[bi];
        r = tanhf(tp[0]) * light;
        g = tanhf(tp[1]) * light;
        b = tanhf(tp[2]) * light;
    }
    out[p]            = r;
    out[NPIX + p]     = g;
    out[2 * NPIX + p] = b;
}

extern "C" void kernel_launch(void* const* d_in, const int* in_sizes, int n_in,
                              void* d_out, int out_size, void* d_ws, size_t ws_size,
                              hipStream_t stream) {
    (void)in_sizes; (void)n_in; (void)d_ws; (void)ws_size; (void)out_size;
    const float* verts = (const float*)d_in[0];
    const int*   faces = (const int*)d_in[1];
    const float* tex   = (const float*)d_in[2];
    float*       out   = (float*)d_out;
    render_kernel<<<NPIX / 256, 256, 0, stream>>>(verts, faces, tex, out);
}

// Round 3
// 37.545 us; speedup vs baseline: 3.6239x; 3.6239x over previous
//
#include <hip/hip_runtime.h>
#include <math.h>

#define NF   640
#define IMGN 256
#define NPIX (IMGN * IMGN)
#define TEXN 6
#define TPB  512            // 8 waves per block
#define PXW  64             // pixels per block (one wave-width row segment)
#define NCH  8              // face chunks == waves per block
#define CHF  (NF / NCH)     // 80 faces per chunk

// Block = 64 consecutive pixels (within one row; 64 | 256 so row-uniform per
// wave). The block's 8 waves each rasterize a disjoint, index-ordered chunk
// of 80 faces for the same 64 pixels; candidates merge via LDS argmin-reduce
// (strict '<' in chunk order == first-occurrence argmin, i.e. jnp.argmin).
//
// CORRECTNESS CONTRACT (bit-exact vs numpy f32 reference, verified R2):
//  - fp contract OFF, true IEEE '/', identical op order on decision path
//  - early-out gate uses numerator/det SIGNS only, which is bit-equivalent
//    to the reference's post-division w1>=0 & w2>=0 test (IEEE sign rules,
//    +-0 >= 0 true under both forms)
//  - degenerate faces (|det|<=1e-8) poisoned so the gate always fails,
//    exactly reproducing "inside & det_ok"
__global__ __launch_bounds__(TPB) void render_kernel(
    const float* __restrict__ verts,   // 400*3 f32
    const int*   __restrict__ faces,   // 640*3 i32
    const float* __restrict__ tex,     // 640*6*6*6*3 f32
    float* __restrict__ out)           // 3*65536 f32 (planar CHW)
{
#pragma clang fp contract(off)
    __shared__ float4 fA[NF];   // {v0x, v0y, ex, ey}
    __shared__ float4 fB[NF];   // {dx, dy, dets, z0}
    __shared__ float4 fC[NF];   // {z1, z2, light, pad}
    __shared__ float rD[NCH][PXW];
    __shared__ int   rI[NCH][PXW];
    __shared__ float rW0[NCH][PXW], rW1[NCH][PXW], rW2[NCH][PXW];

    const float EPSf = 1e-8f;
    const int tid = (int)threadIdx.x;

    // ---- per-face prep (camera rotation exactly identity in f32) ----
    for (int f = tid; f < NF; f += TPB) {
        int ia = faces[3 * f + 0];
        int ib = faces[3 * f + 1];
        int ic = faces[3 * f + 2];
        float ax = verts[3 * ia], ay = verts[3 * ia + 1], az = verts[3 * ia + 2];
        float bx = verts[3 * ib], by = verts[3 * ib + 1], bz = verts[3 * ib + 2];
        float cx = verts[3 * ic], cy = verts[3 * ic + 1], cz = verts[3 * ic + 2];

        // lighting (value-only path)
        float e1x = bx - ax, e1y = by - ay, e1z = bz - az;
        float e2x = cx - ax, e2y = cy - ay, e2z = cz - az;
        float nx = e1y * e2z - e1z * e2y;
        float ny = e1z * e2x - e1x * e2z;
        float nz = e1x * e2y - e1y * e2x;
        float nn = sqrtf((nx * nx + ny * ny) + nz * nz) + EPSf;
        float diff = nz / nn;
        diff = diff > 0.0f ? diff : 0.0f;
        float light = 0.5f + 0.5f * diff;

        // project: vc = [x, y, z+2], wfov = 1.0f exactly
        float z0 = az + 2.0f, z1 = bz + 2.0f, z2 = cz + 2.0f;
        float den0 = z0 * 1.0f + EPSf;
        float den1 = z1 * 1.0f + EPSf;
        float den2 = z2 * 1.0f + EPSf;
        float px0 = ax / den0, py0v = ay / den0;
        float px1 = bx / den1, py1v = by / den1;
        float px2 = cx / den2, py2v = cy / den2;

        float dx = px1 - px0, dy = py1v - py0v;
        float ex = px2 - px0, ey = py2v - py0v;
        float det = dx * ey - dy * ex;
        bool ok = fabsf(det) > 1e-8f;

        if (ok) {
            fA[f] = make_float4(px0, py0v, ex, ey);
            fB[f] = make_float4(dx, dy, det, z0);
            fC[f] = make_float4(z1, z2, light, 0.0f);
        } else {
            // poison: n1 = qx*ey - qy*ex = (ppx - 1e30) < 0, dets = 1 > 0
            // => sign gate always fails => face never accepted (== det_ok mask)
            fA[f] = make_float4(1e30f, 0.0f, 0.0f, 1.0f);
            fB[f] = make_float4(0.0f, 1.0f, 1.0f, 1.0f);
            fC[f] = make_float4(1.0f, 1.0f, 0.0f, 0.0f);
        }
    }
    __syncthreads();

    // ---- raster: wave w handles faces [w*CHF, (w+1)*CHF) for 64 pixels ----
    const int wid  = tid >> 6;
    const int lane = tid & 63;
    const int p    = (int)blockIdx.x * PXW + lane;
    const int pi   = p >> 8;
    const int pj   = p & (IMGN - 1);
    const float ppx = ((pj + 0.5f) / (float)IMGN) * 2.0f - 1.0f;
    const float ppy = -(((pi + 0.5f) / (float)IMGN) * 2.0f - 1.0f);

    float best = 1e30f;
    int   bi = -1;
    float bw0 = 0.0f, bw1 = 0.0f, bw2 = 0.0f;

    const int fbeg = wid * CHF, fend = fbeg + CHF;
    for (int f = fbeg; f < fend; ++f) {
        float4 a = fA[f];                       // v0x v0y ex ey (broadcast)
        float qx = ppx - a.x;
        float qy = ppy - a.y;
        float n1 = qx * a.w - qy * a.z;
        float4 b = fB[f];                       // dx dy dets z0
        float n2 = b.x * qy - b.y * qx;
        // sign gate == (w1>=0 && w2>=0) after IEEE division, bit-exact
        bool pass = (b.z > 0.0f) ? (n1 >= 0.0f && n2 >= 0.0f)
                                 : (n1 <= 0.0f && n2 <= 0.0f);
        if (pass) {
            float w1 = n1 / b.z;
            float w2 = n2 / b.z;
            float w0 = (1.0f - w1) - w2;
            if (w0 >= 0.0f) {
                float4 c = fC[f];               // z1 z2 light
                float depth = ((w0 * b.w) + (w1 * c.x)) + (w2 * c.y);
                if (depth > 0.0f && depth < best) {
                    best = depth; bi = f; bw0 = w0; bw1 = w1; bw2 = w2;
                }
            }
        }
    }

    rD[wid][lane]  = best;
    rI[wid][lane]  = bi;
    rW0[wid][lane] = bw0;
    rW1[wid][lane] = bw1;
    rW2[wid][lane] = bw2;
    __syncthreads();

    // ---- wave 0: argmin-merge 8 chunk candidates, shade, write ----
    if (tid < PXW) {
        float bd = rD[0][tid];
        int   fi = rI[0][tid];
        float w0 = rW0[0][tid], w1 = rW1[0][tid], w2 = rW2[0][tid];
        for (int c = 1; c < NCH; ++c) {
            float d = rD[c][tid];
            if (d < bd) {   // strict <, chunk order ascending => first argmin
                bd = d; fi = rI[c][tid];
                w0 = rW0[c][tid]; w1 = rW1[c][tid]; w2 = rW2[c][tid];
            }
        }

        int pp = (int)blockIdx.x * PXW + tid;
        float r = 0.0f, g = 0.0f, b = 0.0f;
        if (fi >= 0) {
            int i0 = (int)(w0 * (float)TEXN);
            int i1 = (int)(w1 * (float)TEXN);
            int i2 = (int)(w2 * (float)TEXN);
            i0 = i0 < 0 ? 0 : (i0 > TEXN - 1 ? TEXN - 1 : i0);
            i1 = i1 < 0 ? 0 : (i1 > TEXN - 1 ? TEXN - 1 : i1);
            i2 = i2 < 0 ? 0 : (i2 > TEXN - 1 ? TEXN - 1 : i2);
            const float* tp = tex + (size_t)((((fi * TEXN + i0) * TEXN + i1) * TEXN + i2) * 3);
            float light = fC[fi].z;
            r = tanhf(tp[0]) * light;
            g = tanhf(tp[1]) * light;
            b = tanhf(tp[2]) * light;
        }
        out[pp]            = r;
        out[NPIX + pp]     = g;
        out[2 * NPIX + pp] = b;
    }
}

extern "C" void kernel_launch(void* const* d_in, const int* in_sizes, int n_in,
                              void* d_out, int out_size, void* d_ws, size_t ws_size,
                              hipStream_t stream) {
    (void)in_sizes; (void)n_in; (void)d_ws; (void)ws_size; (void)out_size;
    const float* verts = (const float*)d_in[0];
    const int*   faces = (const int*)d_in[1];
    const float* tex   = (const float*)d_in[2];
    float*       out   = (float*)d_out;
    render_kernel<<<NPIX / PXW, TPB, 0, stream>>>(verts, faces, tex, out);
}

// Round 4
// 36.250 us; speedup vs baseline: 3.7533x; 1.0357x over previous
//
#include <hip/hip_runtime.h>
#include <math.h>

#define NF   640
#define IMGN 256
#define NPIX (IMGN * IMGN)
#define TEXN 6
#define TPB  512            // 8 waves
#define PXW  64             // pixels per block (row segment)
#define NCH  8              // face chunks == waves
#define CHF  (NF / NCH)     // 80 faces per chunk

// d_ws record layout (float4 units):
//   rec[0*NF + f] = A  {v0x, v0y, ex, ey}
//   rec[1*NF + f] = B  {dx, dy, dets, z0}
//   rec[2*NF + f] = C  {z1, z2, light, 0}
//   rec[3*NF + f] = BB {xmin-pad, xmax+pad, ymin-pad, ymax+pad}
//
// CORRECTNESS CONTRACT (bit-exact vs numpy f32 ref, verified R2/R3):
//  - fp contract OFF, true IEEE '/', identical op order on decision path
//  - sign gate == post-division w>=0 test (IEEE sign rules)
//  - bbox cull is conservative: pad (extent+1)*1e-6 >> rounding acceptance
//    slack (~extent*2^-23); degenerate faces get empty bbox == det_ok mask

__global__ __launch_bounds__(256) void setup_kernel(
    const float* __restrict__ verts,   // 400*3 f32
    const int*   __restrict__ faces,   // 640*3 i32
    float4* __restrict__ rec)
{
#pragma clang fp contract(off)
    int f = (int)(blockIdx.x * 256 + threadIdx.x);
    if (f >= NF) return;
    const float EPSf = 1e-8f;

    int ia = faces[3 * f + 0];
    int ib = faces[3 * f + 1];
    int ic = faces[3 * f + 2];
    float ax = verts[3 * ia], ay = verts[3 * ia + 1], az = verts[3 * ia + 2];
    float bx = verts[3 * ib], by = verts[3 * ib + 1], bz = verts[3 * ib + 2];
    float cx = verts[3 * ic], cy = verts[3 * ic + 1], cz = verts[3 * ic + 2];

    // lighting (value-only path)
    float e1x = bx - ax, e1y = by - ay, e1z = bz - az;
    float e2x = cx - ax, e2y = cy - ay, e2z = cz - az;
    float nx = e1y * e2z - e1z * e2y;
    float ny = e1z * e2x - e1x * e2z;
    float nz = e1x * e2y - e1y * e2x;
    float nn = sqrtf((nx * nx + ny * ny) + nz * nz) + EPSf;
    float diff = nz / nn;
    diff = diff > 0.0f ? diff : 0.0f;
    float light = 0.5f + 0.5f * diff;

    // project: vc = [x, y, z+2], wfov == 1.0f exactly
    float z0 = az + 2.0f, z1 = bz + 2.0f, z2 = cz + 2.0f;
    float den0 = z0 * 1.0f + EPSf;
    float den1 = z1 * 1.0f + EPSf;
    float den2 = z2 * 1.0f + EPSf;
    float px0 = ax / den0, py0v = ay / den0;
    float px1 = bx / den1, py1v = by / den1;
    float px2 = cx / den2, py2v = cy / den2;

    float dx = px1 - px0, dy = py1v - py0v;
    float ex = px2 - px0, ey = py2v - py0v;
    float det = dx * ey - dy * ex;
    bool ok = fabsf(det) > 1e-8f;

    rec[0 * NF + f] = make_float4(px0, py0v, ex, ey);
    rec[1 * NF + f] = make_float4(dx, dy, ok ? det : 1.0f, z0);
    rec[2 * NF + f] = make_float4(z1, z2, light, 0.0f);

    if (ok) {
        float xmin = fminf(px0, fminf(px1, px2));
        float xmax = fmaxf(px0, fmaxf(px1, px2));
        float ymin = fminf(py0v, fminf(py1v, py2v));
        float ymax = fmaxf(py0v, fmaxf(py1v, py2v));
        float padx = (fmaxf(fabsf(xmin), fabsf(xmax)) + 1.0f) * 1e-6f;
        float pady = (fmaxf(fabsf(ymin), fabsf(ymax)) + 1.0f) * 1e-6f;
        rec[3 * NF + f] = make_float4(xmin - padx, xmax + padx,
                                      ymin - pady, ymax + pady);
    } else {
        // empty bbox: never overlaps any block => face never tested,
        // exactly reproducing the det_ok mask
        rec[3 * NF + f] = make_float4(3e30f, -3e30f, 3e30f, -3e30f);
    }
}

__global__ __launch_bounds__(TPB) void render_kernel(
    const float4* __restrict__ rec,
    const float* __restrict__ tex,    // 640*6*6*6*3 f32
    float* __restrict__ out)          // 3*65536 f32 (planar CHW)
{
#pragma clang fp contract(off)
    __shared__ int   sList[NCH][CHF];
    __shared__ float rD[NCH][PXW];
    __shared__ int   rI[NCH][PXW];
    __shared__ float rW0[NCH][PXW], rW1[NCH][PXW], rW2[NCH][PXW];

    const int tid  = (int)threadIdx.x;
    const int wid  = tid >> 6;
    const int lane = tid & 63;
    const int p0   = (int)blockIdx.x * PXW;
    const int pi   = p0 >> 8;          // row (single row per block)
    const int pj0  = p0 & (IMGN - 1);  // first col

    const float by    = -(((pi + 0.5f) / (float)IMGN) * 2.0f - 1.0f);
    const float bxmin = ((pj0 + 0.5f) / (float)IMGN) * 2.0f - 1.0f;
    const float bxmax = ((pj0 + (PXW - 1) + 0.5f) / (float)IMGN) * 2.0f - 1.0f;

    // ---- cull + ordered ballot-compaction of this wave's 80-face chunk ----
    const int fbeg = wid * CHF;
    int cnt = 0;
    for (int r = 0; r < 2; ++r) {
        int idx = r * 64 + lane;
        int f = fbeg + idx;
        bool pred = false;
        if (idx < CHF) {
            float4 bb = rec[3 * NF + f];  // {xmin,xmax,ymin,ymax} padded
            pred = (bb.x <= bxmax) && (bb.y >= bxmin) &&
                   (bb.z <= by)    && (bb.w >= by);
        }
        unsigned long long m = __ballot(pred);
        if (pred)
            sList[wid][cnt + (int)__popcll(m & ((1ull << lane) - 1ull))] = f;
        cnt += (int)__popcll(m);
    }

    // ---- raster this wave's candidates for the 64 pixels ----
    const float ppx = ((pj0 + lane + 0.5f) / (float)IMGN) * 2.0f - 1.0f;
    const float ppy = by;

    float best = 1e30f;
    int   bi = -1;
    float bw0 = 0.0f, bw1 = 0.0f, bw2 = 0.0f;

    for (int k = 0; k < cnt; ++k) {
        int f = sList[wid][k];
        float4 a = rec[f];            // v0x v0y ex ey (uniform addr, L2)
        float4 b = rec[NF + f];       // dx dy dets z0
        float qx = ppx - a.x;
        float qy = ppy - a.y;
        float n1 = qx * a.w - qy * a.z;
        float n2 = b.x * qy - b.y * qx;
        bool pass = (b.z > 0.0f) ? (n1 >= 0.0f && n2 >= 0.0f)
                                 : (n1 <= 0.0f && n2 <= 0.0f);
        if (pass) {
            float w1 = n1 / b.z;
            float w2 = n2 / b.z;
            float w0 = (1.0f - w1) - w2;
            if (w0 >= 0.0f) {
                float4 c = rec[2 * NF + f];   // z1 z2 light
                float depth = ((w0 * b.w) + (w1 * c.x)) + (w2 * c.y);
                if (depth > 0.0f && depth < best) {
                    best = depth; bi = f; bw0 = w0; bw1 = w1; bw2 = w2;
                }
            }
        }
    }

    rD[wid][lane]  = best;
    rI[wid][lane]  = bi;
    rW0[wid][lane] = bw0;
    rW1[wid][lane] = bw1;
    rW2[wid][lane] = bw2;
    __syncthreads();

    // ---- wave 0: argmin-merge 8 chunks (chunk order => first-occurrence) ----
    if (tid < PXW) {
        float bd = rD[0][tid];
        int   fi = rI[0][tid];
        float w0 = rW0[0][tid], w1 = rW1[0][tid], w2 = rW2[0][tid];
        for (int c = 1; c < NCH; ++c) {
            float d = rD[c][tid];
            if (d < bd) {
                bd = d; fi = rI[c][tid];
                w0 = rW0[c][tid]; w1 = rW1[c][tid]; w2 = rW2[c][tid];
            }
        }

        int pp = p0 + tid;
        float r = 0.0f, g = 0.0f, b = 0.0f;
        if (fi >= 0) {
            int i0 = (int)(w0 * (float)TEXN);
            int i1 = (int)(w1 * (float)TEXN);
            int i2 = (int)(w2 * (float)TEXN);
            i0 = i0 < 0 ? 0 : (i0 > TEXN - 1 ? TEXN - 1 : i0);
            i1 = i1 < 0 ? 0 : (i1 > TEXN - 1 ? TEXN - 1 : i1);
            i2 = i2 < 0 ? 0 : (i2 > TEXN - 1 ? TEXN - 1 : i2);
            const float* tp = tex + (size_t)((((fi * TEXN + i0) * TEXN + i1) * TEXN + i2) * 3);
            float light = rec[2 * NF + fi].z;
            r = tanhf(tp[0]) * light;
            g = tanhf(tp[1]) * light;
            b = tanhf(tp[2]) * light;
        }
        out[pp]            = r;
        out[NPIX + pp]     = g;
        out[2 * NPIX + pp] = b;
    }
}

extern "C" void kernel_launch(void* const* d_in, const int* in_sizes, int n_in,
                              void* d_out, int out_size, void* d_ws, size_t ws_size,
                              hipStream_t stream) {
    (void)in_sizes; (void)n_in; (void)ws_size; (void)out_size;
    const float* verts = (const float*)d_in[0];
    const int*   faces = (const int*)d_in[1];
    const float* tex   = (const float*)d_in[2];
    float*       out   = (float*)d_out;
    float4*      rec   = (float4*)d_ws;   // needs 4*640*16 = 40 KB

    setup_kernel<<<(NF + 255) / 256, 256, 0, stream>>>(verts, faces, rec);
    render_kernel<<<NPIX / PXW, TPB, 0, stream>>>(rec, tex, out);
}

// Round 5
// 27.451 us; speedup vs baseline: 4.9564x; 1.3205x over previous
//
#include <hip/hip_runtime.h>
#include <math.h>

#define NF   640
#define IMGN 256
#define NPIX (IMGN * IMGN)
#define TEXN 6
#define TPB  512            // 8 waves
#define PXW  64             // pixels per block (row segment)
#define NCH  8              // face chunks == waves
#define CHF  (NF / NCH)     // 80 faces per chunk

// Single kernel. Block = 64 consecutive pixels of one row. Wave w:
//   1) computes per-face records for its 80-face chunk (registers),
//      stores {A,B,C} to LDS, bbox-culls against the block's strip in
//      registers, ballot-compacts survivors (ascending f) to sList.
//   2) rasterizes its candidates for all 64 pixels from LDS (broadcast
//      ds_read_b128 — LDS-throughput, not global-latency).
//   3) per-pixel argmin-merge across the 8 chunks (chunk-ascending,
//      strict '<' == jnp.argmin first-occurrence), shade, write.
//
// CORRECTNESS CONTRACT (bit-exact vs numpy f32 ref, verified R2-R4):
//  - fp contract OFF, true IEEE '/', identical op order on decision path
//  - sign gate == post-division w>=0 test (IEEE sign rules)
//  - bbox cull conservative (pad (ext+1)*1e-6 >> ~ext*2^-23 accept slack);
//    degenerate faces never listed == det_ok mask
//  - shade recomputes w0/w1/w2 with identical ops on identical LDS values
//    => bit-identical to the values that won the argmin
__global__ __launch_bounds__(TPB) void render_kernel(
    const float* __restrict__ verts,   // 400*3 f32
    const int*   __restrict__ faces,   // 640*3 i32
    const float* __restrict__ tex,     // 640*6*6*6*3 f32
    float* __restrict__ out)           // 3*65536 f32 (planar CHW)
{
#pragma clang fp contract(off)
    __shared__ float4 fAB[NF * 2];    // [2f]=A{v0x,v0y,ex,ey} [2f+1]=B{dx,dy,det,z0}
    __shared__ float4 fC[NF];         // {z1,z2,light,0}
    __shared__ unsigned short sList[NCH][CHF];
    __shared__ float rD[NCH][PXW];
    __shared__ int   rI[NCH][PXW];
    // total LDS = 20480 + 10240 + 1280 + 2048 + 2048 = 36096 B -> 4 blocks/CU

    const float EPSf = 1e-8f;
    const int tid  = (int)threadIdx.x;
    const int wid  = tid >> 6;
    const int lane = tid & 63;
    const int p0   = (int)blockIdx.x * PXW;
    const int pi   = p0 >> 8;          // row (uniform per block)
    const int pj0  = p0 & (IMGN - 1);  // first col

    const float by    = -(((pi + 0.5f) / (float)IMGN) * 2.0f - 1.0f);
    const float bxmin = ((pj0 + 0.5f) / (float)IMGN) * 2.0f - 1.0f;
    const float bxmax = ((pj0 + (PXW - 1) + 0.5f) / (float)IMGN) * 2.0f - 1.0f;

    // ---- fused setup + cull: wave w owns faces [80w, 80w+80) ----
    const int fbeg = wid * CHF;
    int cnt = 0;
    for (int r = 0; r < 2; ++r) {
        int idx = r * 64 + lane;
        int f = fbeg + idx;
        bool pred = false;
        if (idx < CHF) {
            int ia = faces[3 * f + 0];
            int ib = faces[3 * f + 1];
            int ic = faces[3 * f + 2];
            float ax = verts[3 * ia], ay = verts[3 * ia + 1], az = verts[3 * ia + 2];
            float bx = verts[3 * ib], byy = verts[3 * ib + 1], bz = verts[3 * ib + 2];
            float cx = verts[3 * ic], cy = verts[3 * ic + 1], cz = verts[3 * ic + 2];

            // lighting (value-only path)
            float e1x = bx - ax, e1y = byy - ay, e1z = bz - az;
            float e2x = cx - ax, e2y = cy - ay, e2z = cz - az;
            float nx = e1y * e2z - e1z * e2y;
            float ny = e1z * e2x - e1x * e2z;
            float nz = e1x * e2y - e1y * e2x;
            float nn = sqrtf((nx * nx + ny * ny) + nz * nz) + EPSf;
            float diff = nz / nn;
            diff = diff > 0.0f ? diff : 0.0f;
            float light = 0.5f + 0.5f * diff;

            // project: vc = [x, y, z+2], wfov == 1.0f exactly
            float z0 = az + 2.0f, z1 = bz + 2.0f, z2 = cz + 2.0f;
            float den0 = z0 * 1.0f + EPSf;
            float den1 = z1 * 1.0f + EPSf;
            float den2 = z2 * 1.0f + EPSf;
            float px0 = ax / den0, py0 = ay / den0;
            float px1 = bx / den1, py1 = byy / den1;
            float px2 = cx / den2, py2 = cy / den2;

            float dx = px1 - px0, dy = py1 - py0;
            float ex = px2 - px0, ey = py2 - py0;
            float det = dx * ey - dy * ex;
            bool ok = fabsf(det) > 1e-8f;

            fAB[2 * f]     = make_float4(px0, py0, ex, ey);
            fAB[2 * f + 1] = make_float4(dx, dy, ok ? det : 1.0f, z0);
            fC[f]          = make_float4(z1, z2, light, 0.0f);

            if (ok) {
                float xmin = fminf(px0, fminf(px1, px2));
                float xmax = fmaxf(px0, fmaxf(px1, px2));
                float ymin = fminf(py0, fminf(py1, py2));
                float ymax = fmaxf(py0, fmaxf(py1, py2));
                float padx = (fmaxf(fabsf(xmin), fabsf(xmax)) + 1.0f) * 1e-6f;
                float pady = (fmaxf(fabsf(ymin), fabsf(ymax)) + 1.0f) * 1e-6f;
                pred = (xmin - padx <= bxmax) && (xmax + padx >= bxmin) &&
                       (ymin - pady <= by)    && (ymax + pady >= by);
            }
        }
        unsigned long long m = __ballot(pred);
        if (pred)
            sList[wid][cnt + (int)__popcll(m & ((1ull << lane) - 1ull))] =
                (unsigned short)f;
        cnt += (int)__popcll(m);
    }

    // ---- raster this wave's candidates (LDS broadcast reads) ----
    const float ppx = ((pj0 + lane + 0.5f) / (float)IMGN) * 2.0f - 1.0f;
    const float ppy = by;

    float best = 1e30f;
    int   bi = -1;

    for (int k = 0; k < cnt; ++k) {
        int f = (int)sList[wid][k];
        float4 a = fAB[2 * f];        // v0x v0y ex ey
        float4 b = fAB[2 * f + 1];    // dx dy det z0
        float qx = ppx - a.x;
        float qy = ppy - a.y;
        float n1 = qx * a.w - qy * a.z;
        float n2 = b.x * qy - b.y * qx;
        // sign gate == (w1>=0 && w2>=0) after IEEE division, bit-exact
        bool pass = (b.z > 0.0f) ? (n1 >= 0.0f && n2 >= 0.0f)
                                 : (n1 <= 0.0f && n2 <= 0.0f);
        if (pass) {
            float w1 = n1 / b.z;
            float w2 = n2 / b.z;
            float w0 = (1.0f - w1) - w2;
            if (w0 >= 0.0f) {
                float4 c = fC[f];     // z1 z2 light
                float depth = ((w0 * b.w) + (w1 * c.x)) + (w2 * c.y);
                if (depth > 0.0f && depth < best) {
                    best = depth; bi = f;
                }
            }
        }
    }

    rD[wid][lane] = best;
    rI[wid][lane] = bi;
    __syncthreads();

    // ---- wave 0: argmin-merge 8 chunks, recompute w, shade, write ----
    if (tid < PXW) {
        float bd = rD[0][tid];
        int   fi = rI[0][tid];
        for (int c = 1; c < NCH; ++c) {
            float d = rD[c][tid];
            if (d < bd) { bd = d; fi = rI[c][tid]; }  // chunk-ascending, strict <
        }

        int pp = p0 + tid;
        float r = 0.0f, g = 0.0f, b = 0.0f;
        if (fi >= 0) {
            // recompute barycentrics: identical ops on identical LDS values
            float4 a2 = fAB[2 * fi];
            float4 b2 = fAB[2 * fi + 1];
            float sx = ((pj0 + tid + 0.5f) / (float)IMGN) * 2.0f - 1.0f;
            float qx = sx - a2.x;
            float qy = by - a2.y;
            float n1 = qx * a2.w - qy * a2.z;
            float n2 = b2.x * qy - b2.y * qx;
            float w1 = n1 / b2.z;
            float w2 = n2 / b2.z;
            float w0 = (1.0f - w1) - w2;

            int i0 = (int)(w0 * (float)TEXN);
            int i1 = (int)(w1 * (float)TEXN);
            int i2 = (int)(w2 * (float)TEXN);
            i0 = i0 < 0 ? 0 : (i0 > TEXN - 1 ? TEXN - 1 : i0);
            i1 = i1 < 0 ? 0 : (i1 > TEXN - 1 ? TEXN - 1 : i1);
            i2 = i2 < 0 ? 0 : (i2 > TEXN - 1 ? TEXN - 1 : i2);
            const float* tp = tex + (size_t)((((fi * TEXN + i0) * TEXN + i1) * TEXN + i2) * 3);
            float light = fC[fi].z;
            r = tanhf(tp[0]) * light;
            g = tanhf(tp[1]) * light;
            b = tanhf(tp[2]) * light;
        }
        out[pp]            = r;
        out[NPIX + pp]     = g;
        out[2 * NPIX + pp] = b;
    }
}

extern "C" void kernel_launch(void* const* d_in, const int* in_sizes, int n_in,
                              void* d_out, int out_size, void* d_ws, size_t ws_size,
                              hipStream_t stream) {
    (void)in_sizes; (void)n_in; (void)d_ws; (void)ws_size; (void)out_size;
    const float* verts = (const float*)d_in[0];
    const int*   faces = (const int*)d_in[1];
    const float* tex   = (const float*)d_in[2];
    float*       out   = (float*)d_out;
    render_kernel<<<NPIX / PXW, TPB, 0, stream>>>(verts, faces, tex, out);
}